// Round 11
// baseline (270.619 us; speedup 1.0000x reference)
//
#include <hip/hip_runtime.h>
#include <hip/hip_bf16.h>

typedef unsigned short u16;
typedef unsigned int   u32;
typedef __attribute__((ext_vector_type(4))) float f32x4;
typedef __attribute__((ext_vector_type(4))) u32   u32x4;
typedef __attribute__((ext_vector_type(8))) short bf16x8;

#define HWPIX  9216
#define NPIX   73728
#define LN_EPS 1e-5f
#define MROW   64       // pixels per block
#define HSTR   264      // hn row stride (elems): 256 + 8 pad (incl. 2-ch wrap pad)
#define ASTR   40       // afg chunk row stride (elems): 32 + 8 pad

template<int N> struct IC { static constexpr int value = N; };

__device__ __forceinline__ u16 f2bf(float f){
  u32 u = __builtin_bit_cast(u32, f);
  u += 0x7fffu + ((u >> 16) & 1u);          // RTNE
  return (u16)(u >> 16);
}
__device__ __forceinline__ u32 pkbf(float lo, float hi){   // 1 inst packed cvt
  u32 d;
  asm("v_cvt_pk_bf16_f32 %0, %1, %2" : "=v"(d) : "v"(lo), "v"(hi));
  return d;
}
__device__ __forceinline__ float lo2f(u32 w){ return __builtin_bit_cast(float, w << 16); }
__device__ __forceinline__ float hi2f(u32 w){ return __builtin_bit_cast(float, w & 0xffff0000u); }
__device__ __forceinline__ float bfu2f(u16 h){ return __builtin_bit_cast(float, (u32)h << 16); }
__device__ __forceinline__ float fsigmoid(float v){ return __fdividef(1.f, 1.f + __expf(-v)); }
__device__ __forceinline__ float fsilu(float v){ return __fdividef(v, 1.f + __expf(-v)); }

// ---------------- kernel 1: weight convert into per-(chunk,wave,fragment) layout ----
// layout: [chunk][wc(4)][nt(4)][lane(64)][8 u16]; chunk = 16KB = 8192 u16.
// slot value: B[n][k], n = wc*64 + nt*16 + (lane&15), k = kbase + (lane>>4)*8 + e.
// A wave's per-step data = contiguous 4KB; each load instr is unit-stride 16B/lane.
__global__ __launch_bounds__(256) void wconv(const float* __restrict__ pk,
                                             const float* __restrict__ gk,
                                             u16* __restrict__ wsdot,   // 16 chunks
                                             u16* __restrict__ wsgate)  // 16 chunks
{
  int gid = blockIdx.x * 256 + threadIdx.x;   // 32768 = 128 blocks
  int t = gid >> 10, S = gid & 1023;
  int wc = S >> 8, nt = (S >> 6) & 3, lane = S & 63;
  int fr = lane & 15, kq = lane >> 4;
  int n  = wc * 64 + nt * 16 + fr;
  const float* W; int k0; u16* dst;
  if (t < 8)       { W = pk; k0 =       t      * 32; dst = wsdot  + (size_t)t * 8192; }
  else if (t < 16) { W = pk; k0 = 512 + (t-8)  * 32; dst = wsdot  + (size_t)t * 8192; }
  else if (t < 24) { W = gk; k0 =       (t-16) * 32; dst = wsgate + (size_t)(t-16) * 8192; }
  else             { W = gk; k0 = 256 + (t-24) * 32; dst = wsgate + (size_t)(t-24) * 8192; }
  int kb = k0 + kq * 8;
  u32 ow[4];
  #pragma unroll
  for (int e = 0; e < 4; ++e) {
    float f0 = W[(size_t)(kb + 2*e)     * 256 + n];
    float f1 = W[(size_t)(kb + 2*e + 1) * 256 + n];
    ow[e] = (u32)f2bf(f0) | ((u32)f2bf(f1) << 16);
  }
  *(u32x4*)(dst + (size_t)S * 8) = (u32x4){ow[0], ow[1], ow[2], ow[3]};
}

// ---------------- kernel 2: per-(b,h) partial sums of h_norm over w ----------------
__global__ __launch_bounds__(256) void ln_partial(const float* __restrict__ x,
                                                  const float* __restrict__ g,
                                                  const float* __restrict__ bt,
                                                  float* __restrict__ partial) // [768][256]
{
  const int bh = blockIdx.x;
  const int tid = threadIdx.x;
  const int wv = tid >> 6, lane = tid & 63;
  const float* xrow = x + (size_t)bh * 96 * 256;
  __shared__ float red[4][256];

  f32x4 gv = *(const f32x4*)(g  + lane * 4);
  f32x4 bv = *(const f32x4*)(bt + lane * 4);
  f32x4 acc = {0.f, 0.f, 0.f, 0.f};

  for (int w = wv; w < 96; w += 4) {
    f32x4 v = *(const f32x4*)(xrow + w * 256 + lane * 4);
    float s  = v[0] + v[1] + v[2] + v[3];
    float s2 = v[0]*v[0] + v[1]*v[1] + v[2]*v[2] + v[3]*v[3];
    #pragma unroll
    for (int m = 1; m < 64; m <<= 1) { s += __shfl_xor(s, m); s2 += __shfl_xor(s2, m); }
    float mu  = s * (1.f / 256.f);
    float var = s2 * (1.f / 256.f) - mu * mu;
    float rs  = rsqrtf(var + LN_EPS);
    #pragma unroll
    for (int j = 0; j < 4; ++j) acc[j] += (v[j] - mu) * rs * gv[j] + bv[j];
  }
  *(f32x4*)(&red[wv][lane * 4]) = acc;
  __syncthreads();
  float s = red[0][tid] + red[1][tid] + red[2][tid] + red[3][tid];
  partial[(size_t)bh * 256 + tid] = s;
}

// ---------------- kernel 3: reduce rows -> spatial mean [8][258] (wrap-padded) -----
__global__ __launch_bounds__(256) void ln_mean(const float* __restrict__ partial,
                                               float* __restrict__ mean)
{
  int b = blockIdx.x, c = threadIdx.x;
  float s = 0.f;
  for (int h = 0; h < 96; ++h) s += partial[((size_t)b * 96 + h) * 256 + c];
  float m = s * (1.f / 9216.f);
  mean[b * 258 + c] = m;
  if (c < 2) mean[b * 258 + 256 + c] = m;
}

// ---------------- kernel 4: fold wedge into per-batch weights (new layout) ---------
__global__ __launch_bounds__(256) void wfold(const float* __restrict__ pk,
                                             const float* __restrict__ meang,
                                             u16* __restrict__ wsW)
{
  __shared__ float msh[256];
  int gid = blockIdx.x * 256 + threadIdx.x;   // 65536 = 256 blocks
  int chunk = gid >> 10;                      // 0..63 (uniform per block)
  int b = chunk >> 3, j = chunk & 7;
  msh[threadIdx.x] = meang[b * 258 + threadIdx.x];
  __syncthreads();
  int S = gid & 1023;
  int wc = S >> 8, nt = (S >> 6) & 3, lane = S & 63;
  int fr = lane & 15, kq = lane >> 4;
  int n  = wc * 64 + nt * 16 + fr;
  u32 ow[4];
  #pragma unroll
  for (int e = 0; e < 4; ++e) {
    float r[2];
    #pragma unroll
    for (int hh = 0; hh < 2; ++hh) {
      int c = j * 32 + kq * 8 + 2 * e + hh;
      int cm1 = (c + 255) & 255, cm2 = (c + 254) & 255;
      int cp1 = (c + 1) & 255,   cp2 = (c + 2) & 255;
      r[hh] = msh[cm1] * pk[(size_t)(256 + cm1) * 256 + n]
            - msh[cp1] * pk[(size_t)(256 + c)   * 256 + n]
            + msh[cm2] * pk[(size_t)(768 + cm2) * 256 + n]
            - msh[cp2] * pk[(size_t)(768 + c)   * 256 + n];
    }
    ow[e] = (u32)f2bf(r[0]) | ((u32)f2bf(r[1]) << 16);
  }
  *(u32x4*)(wsW + (size_t)chunk * 8192 + (size_t)S * 8) = (u32x4){ow[0], ow[1], ow[2], ow[3]};
}

// ---------------- kernel 5: fused main ---------------------------------------------
// 64 pixels/block, 512 threads (8 waves 2x4). B loaded straight into REGISTERS
// (parity ring) from the per-wave-contiguous layout; feats computed LANE-LOCALLY as
// the MFMA A-operand. Steps 0..30 are barrier-free (hn/mshp read-only, rest in regs);
// only the 8 g_feat redistribution steps keep __syncthreads. LDS 46KB.
__global__ __launch_bounds__(512, 4) void fused(
    const float* __restrict__ x,
    const float* __restrict__ lng, const float* __restrict__ lnb,
    const u16* __restrict__ wsdot, const u16* __restrict__ wsW,
    const u16* __restrict__ wsgate,
    const float* __restrict__ pbias, const float* __restrict__ gbias,
    const float* __restrict__ gamma, const float* __restrict__ meang,
    float* __restrict__ out)
{
  __shared__ u16 hn[MROW * HSTR];       // 33792 B  h_norm bf16 (persists, read-only after preproc)
  __shared__ u16 afg[2][MROW * ASTR];   // 10240 B  g_feat chunk dbuf (seg 4 only)
  __shared__ float mshp[2][256];        //  2048 B  mshp[s-1][c] = mean[c+s]

  const int tid  = threadIdx.x;
  const long pix0 = (long)blockIdx.x * MROW;
  const int bat  = (int)(pix0 / HWPIX);      // 9216 % 64 == 0

  const int wave = tid >> 6, lane = tid & 63;
  const int wr = wave & 1, wc = wave >> 1;       // 2x4 wave grid
  const int fr = lane & 15, kq = lane >> 4;

  if (tid < 256) {
    mshp[0][tid] = meang[bat * 258 + tid + 1];
    mshp[1][tid] = meang[bat * 258 + tid + 2];
  }

  f32x4 acc[2][4];
  #pragma unroll
  for (int i = 0; i < 2; ++i)
    #pragma unroll
    for (int j = 0; j < 4; ++j) acc[i][j] = (f32x4){0.f, 0.f, 0.f, 0.f};
  u32 gfp[2][4][2];

  // ---- B register ring: two named sets, parity = chunk & 1 ----
  u32x4 b0[4], b1[4];
  auto sgbase = [&](auto SEGC) -> const u16* {
    constexpr int sg = decltype(SEGC)::value;
    if constexpr      (sg == 0) return wsdot;
    else if constexpr (sg == 1) return wsdot + 8 * 8192;
    else if constexpr (sg == 2) return wsW + (size_t)bat * 65536;
    else if constexpr (sg == 3) return wsgate;
    else                        return wsgate + 8 * 8192;
  };
  auto loadB = [&](auto CH) {
    constexpr int ch = decltype(CH)::value;
    const u16* s0 = sgbase(IC<(ch >> 3)>{}) + (size_t)(ch & 7) * 8192 + wc * 2048 + lane * 8;
    if constexpr ((ch & 1) == 0) {
      b0[0] = *(const u32x4*)(s0);        b0[1] = *(const u32x4*)(s0 + 512);
      b0[2] = *(const u32x4*)(s0 + 1024); b0[3] = *(const u32x4*)(s0 + 1536);
    } else {
      b1[0] = *(const u32x4*)(s0);        b1[1] = *(const u32x4*)(s0 + 512);
      b1[2] = *(const u32x4*)(s0 + 1024); b1[3] = *(const u32x4*)(s0 + 1536);
    }
  };

  loadB(IC<0>{});                     // chunk 0 -> set 0; lands during preproc

  float pbv[4];
  #pragma unroll
  for (int nt = 0; nt < 4; ++nt) pbv[nt] = pbias[wc * 64 + nt * 16 + fr];

  // ---- preproc (2-pass): LN -> hn (8 lanes/pixel, 32 ch each) ----
  {
    const int p = tid >> 3, o = tid & 7;
    const float* xp = x + (pix0 + p) * 256 + o * 32;
    float s = 0.f, s2 = 0.f;
    #pragma unroll
    for (int i = 0; i < 8; ++i) {
      f32x4 v = *(const f32x4*)(xp + i * 4);
      s  += v[0] + v[1] + v[2] + v[3];
      s2 += v[0]*v[0] + v[1]*v[1] + v[2]*v[2] + v[3]*v[3];
    }
    s += __shfl_xor(s, 1); s2 += __shfl_xor(s2, 1);
    s += __shfl_xor(s, 2); s2 += __shfl_xor(s2, 2);
    s += __shfl_xor(s, 4); s2 += __shfl_xor(s2, 4);
    float mu  = s * (1.f / 256.f);
    float var = s2 * (1.f / 256.f) - mu * mu;
    float rs  = rsqrtf(var + LN_EPS);

    const float* gp = lng + o * 32;
    const float* bp = lnb + o * 32;
    u16* zd = hn + p * HSTR + o * 32;
    #pragma unroll
    for (int i = 0; i < 8; ++i) {
      f32x4 v  = *(const f32x4*)(xp + i * 4);     // L2-hot reload
      f32x4 gg = *(const f32x4*)(gp + i * 4);
      f32x4 bb = *(const f32x4*)(bp + i * 4);
      float h0 = (v[0] - mu) * rs * gg[0] + bb[0];
      float h1 = (v[1] - mu) * rs * gg[1] + bb[1];
      float h2 = (v[2] - mu) * rs * gg[2] + bb[2];
      float h3 = (v[3] - mu) * rs * gg[3] + bb[3];
      u32 d0 = pkbf(h0, h1);
      u32 d1 = pkbf(h2, h3);
      *(u32*)(zd + i * 4)     = d0;
      *(u32*)(zd + i * 4 + 2) = d1;
      if (i == 0 && o == 0) *(u32*)(hn + p * HSTR + 256) = d0;  // wrap pad ch[256,257]
    }
  }

  // lane-local feats: A fragment for shift s, window w, one hn row -> bf16x8
  auto featsRow = [&](auto SC, int w, int row) -> bf16x8 {
    constexpr int s = decltype(SC)::value;
    const int cc = w * 32 + kq * 8;
    const u16* zp = hn + row * HSTR + cc;
    u32x4 hv = *(const u32x4*)(zp);            // h0..h7
    u32  hx  = *(const u32*)(zp + 8);          // h8,h9
    float h0 = lo2f(hv[0]), h1 = hi2f(hv[0]), h2 = lo2f(hv[1]), h3 = hi2f(hv[1]);
    float h4 = lo2f(hv[2]), h5 = hi2f(hv[2]), h6 = lo2f(hv[3]), h7 = hi2f(hv[3]);
    float h8 = lo2f(hx),  h9 = hi2f(hx);
    const float* mp = &mshp[s - 1][cc];        // broadcast within 16-lane group
    f32x4 ma = *(const f32x4*)(mp);
    f32x4 mb = *(const f32x4*)(mp + 4);
    float t0, t1, t2, t3, t4, t5, t6, t7;
    if constexpr (s == 1) { t0=h1; t1=h2; t2=h3; t3=h4; t4=h5; t5=h6; t6=h7; t7=h8; }
    else                  { t0=h2; t1=h3; t2=h4; t3=h5; t4=h6; t5=h7; t6=h8; t7=h9; }
    float r0 = fsilu(h0 * (t0 - ma[0]));
    float r1 = fsilu(h1 * (t1 - ma[1]));
    float r2 = fsilu(h2 * (t2 - ma[2]));
    float r3 = fsilu(h3 * (t3 - ma[3]));
    float r4 = fsilu(h4 * (t4 - mb[0]));
    float r5 = fsilu(h5 * (t5 - mb[1]));
    float r6 = fsilu(h6 * (t6 - mb[2]));
    float r7 = fsilu(h7 * (t7 - mb[3]));
    u32x4 o_;
    o_[0] = pkbf(r0, r1); o_[1] = pkbf(r2, r3);
    o_[2] = pkbf(r4, r5); o_[3] = pkbf(r6, r7);
    return __builtin_bit_cast(bf16x8, o_);
  };

  // g_feat chunk cg (compile-time) from packed regs into afg (seg 4 only)
  auto gfcopy = [&](auto CGC, int buf) {
    constexpr int cg = decltype(CGC)::value;
    constexpr int par = cg & 1;
    if (wc == (cg >> 1)) {
      #pragma unroll
      for (int v = 0; v < 2; ++v) {
        #pragma unroll
        for (int ai = 0; ai < 2; ++ai)
          #pragma unroll
          for (int rp = 0; rp < 2; ++rp) {
            u32 pw = gfp[ai][par * 2 + v][rp];
            int row0 = wr * 32 + ai * 16 + kq * 4 + rp * 2;
            afg[buf][row0 * ASTR + v * 16 + fr]       = (u16)pw;
            afg[buf][(row0 + 1) * ASTR + v * 16 + fr] = (u16)(pw >> 16);
          }
      }
    }
  };

  auto domfma = [&](bf16x8 av0, bf16x8 av1, auto PAR) {
    __builtin_amdgcn_s_setprio(1);
    #pragma unroll
    for (int nt = 0; nt < 4; ++nt) {
      bf16x8 bv;
      if constexpr (decltype(PAR)::value == 0) bv = __builtin_bit_cast(bf16x8, b0[nt]);
      else                                     bv = __builtin_bit_cast(bf16x8, b1[nt]);
      acc[0][nt] = __builtin_amdgcn_mfma_f32_16x16x32_bf16(av0, bv, acc[0][nt], 0, 0, 0);
      acc[1][nt] = __builtin_amdgcn_mfma_f32_16x16x32_bf16(av1, bv, acc[1][nt], 0, 0, 0);
    }
    __builtin_amdgcn_s_setprio(0);
  };

  __syncthreads();                    // hn, mshp visible — the ONLY barrier until seg 4

  auto stepfn = [&](auto TC) {
    constexpr int t   = decltype(TC)::value;
    constexpr int seg = t >> 3, loc = t & 7;
    constexpr int u   = t + 1;
    if constexpr (u < 40) loadB(IC<u>{});     // into set (u&1); used next step
    bf16x8 av0, av1;
    if constexpr (seg == 0) {
      av0 = featsRow(IC<1>{}, loc, wr * 32 + fr);
      av1 = featsRow(IC<1>{}, loc, wr * 32 + 16 + fr);
    } else if constexpr (seg == 1) {
      av0 = featsRow(IC<2>{}, loc, wr * 32 + fr);
      av1 = featsRow(IC<2>{}, loc, wr * 32 + 16 + fr);
    } else if constexpr (seg == 2 || seg == 3) {
      const u16* ar = hn + (wr * 32 + fr) * HSTR + loc * 32 + kq * 8;
      av0 = *(const bf16x8*)(ar);
      av1 = *(const bf16x8*)(ar + 16 * HSTR);
    } else {
      const u16* ar = &afg[t & 1][(wr * 32 + fr) * ASTR + kq * 8];
      av0 = *(const bf16x8*)(ar);
      av1 = *(const bf16x8*)(ar + 16 * ASTR);
    }
    domfma(av0, av1, IC<t & 1>{});
    if constexpr (t == 23) {          // end of GEMM1: fold to packed bf16 g_feat
      #pragma unroll
      for (int nt = 0; nt < 4; ++nt)
        #pragma unroll
        for (int ai = 0; ai < 2; ++ai) {
          f32x4 a = acc[ai][nt];
          gfp[ai][nt][0] = pkbf(a[0] + pbv[nt], a[1] + pbv[nt]);
          gfp[ai][nt][1] = pkbf(a[2] + pbv[nt], a[3] + pbv[nt]);
          acc[ai][nt] = (f32x4){0.f, 0.f, 0.f, 0.f};
        }
    }
    if constexpr (t >= 31 && t < 39) {        // produce g_feat A-chunk for step t+1
      gfcopy(IC<t - 31>{}, (t + 1) & 1);
      __syncthreads();
    }
  };
  auto run8 = [&](auto B8) {
    constexpr int b8 = decltype(B8)::value;
    stepfn(IC<b8 + 0>{}); stepfn(IC<b8 + 1>{}); stepfn(IC<b8 + 2>{}); stepfn(IC<b8 + 3>{});
    stepfn(IC<b8 + 4>{}); stepfn(IC<b8 + 5>{}); stepfn(IC<b8 + 6>{}); stepfn(IC<b8 + 7>{});
  };
  run8(IC<0>{}); run8(IC<8>{}); run8(IC<16>{}); run8(IC<24>{}); run8(IC<32>{});

  // ---- final epilogue: alpha, silu, LayerScale, residual ----
  float gbv[4], gmv[4];
  #pragma unroll
  for (int nt = 0; nt < 4; ++nt) {
    int col = wc * 64 + nt * 16 + fr;
    gbv[nt] = gbias[col]; gmv[nt] = gamma[col];
  }
  #pragma unroll
  for (int ai = 0; ai < 2; ++ai)
    #pragma unroll
    for (int rr = 0; rr < 4; ++rr) {
      const int row = wr * 32 + ai * 16 + kq * 4 + rr;
      const long pix = pix0 + row;
      #pragma unroll
      for (int nt = 0; nt < 4; ++nt) {
        int col = wc * 64 + nt * 16 + fr;
        float xv = x[pix * 256 + col];
        float hh = bfu2f(hn[row * HSTR + col]);
        u32 pw = gfp[ai][nt][rr >> 1];
        float gfv = bfu2f((u16)((rr & 1) ? (pw >> 16) : pw));
        float al = fsigmoid(acc[ai][nt][rr] + gbv[nt]);
        out[pix * 256 + col] = xv + (fsilu(hh) + al * gfv) * gmv[nt];
      }
    }
}

extern "C" void kernel_launch(void* const* d_in, const int* in_sizes, int n_in,
                              void* d_out, int out_size, void* d_ws, size_t ws_size,
                              hipStream_t stream) {
  const float* x     = (const float*)d_in[0];
  const float* lng   = (const float*)d_in[1];
  const float* lnb   = (const float*)d_in[2];
  const float* pk    = (const float*)d_in[3];
  const float* pbias = (const float*)d_in[4];
  const float* gk    = (const float*)d_in[5];
  const float* gbias = (const float*)d_in[6];
  const float* gamma = (const float*)d_in[7];
  float* out = (float*)d_out;

  char* ws = (char*)d_ws;
  u16*   wsdot   = (u16*)ws;                       // 262144 B (16 chunks)
  u16*   wsgate  = (u16*)(ws + 262144);            // 262144 B (16 chunks)
  float* meang   = (float*)(ws + 524288);          // 8256 B
  u16*   wsW     = (u16*)(ws + 532544);            // 1048576 B (64 chunks, per-batch W')
  float* partial = (float*)(ws + 532544);          // 786432 B — dead before wfold writes W'

  wconv<<<128, 256, 0, stream>>>(pk, gk, wsdot, wsgate);
  ln_partial<<<768, 256, 0, stream>>>(x, lng, lnb, partial);
  ln_mean<<<8, 256, 0, stream>>>(partial, meang);
  wfold<<<256, 256, 0, stream>>>(pk, meang, wsW);
  fused<<<NPIX / MROW, 512, 0, stream>>>(x, lng, lnb, wsdot, wsW, wsgate,
                                         pbias, gbias, gamma, meang, out);
}

// Round 12
// 224.817 us; speedup vs baseline: 1.2037x; 1.2037x over previous
//
#include <hip/hip_runtime.h>
#include <hip/hip_bf16.h>

typedef unsigned short u16;
typedef unsigned int   u32;
typedef __attribute__((ext_vector_type(4))) float f32x4;
typedef __attribute__((ext_vector_type(4))) u32   u32x4;
typedef __attribute__((ext_vector_type(8))) short bf16x8;

#define HWPIX  9216
#define NPIX   73728
#define LN_EPS 1e-5f
#define MROW   64       // pixels per block
#define HSTR   264      // hn row stride (elems): 256 + 8 pad (incl. 2-ch wrap pad)
#define ASTR   40       // afg chunk row stride (elems): 32 + 8 pad

template<int N> struct IC { static constexpr int value = N; };

__device__ __forceinline__ u16 f2bf(float f){
  u32 u = __builtin_bit_cast(u32, f);
  u += 0x7fffu + ((u >> 16) & 1u);          // RTNE
  return (u16)(u >> 16);
}
__device__ __forceinline__ u32 pkbf(float lo, float hi){   // 1 inst packed cvt
  u32 d;
  asm("v_cvt_pk_bf16_f32 %0, %1, %2" : "=v"(d) : "v"(lo), "v"(hi));
  return d;
}
__device__ __forceinline__ float lo2f(u32 w){ return __builtin_bit_cast(float, w << 16); }
__device__ __forceinline__ float hi2f(u32 w){ return __builtin_bit_cast(float, w & 0xffff0000u); }
__device__ __forceinline__ float bfu2f(u16 h){ return __builtin_bit_cast(float, (u32)h << 16); }
__device__ __forceinline__ float fsigmoid(float v){ return __fdividef(1.f, 1.f + __expf(-v)); }
__device__ __forceinline__ float fsilu(float v){ return __fdividef(v, 1.f + __expf(-v)); }

// ---------------- kernel 1: weight convert into per-(chunk,wave,fragment) layout ----
// layout: [chunk][wc(4)][nt(4)][lane(64)][8 u16]; chunk = 16KB = 8192 u16.
// slot value: B[n][k], n = wc*64 + nt*16 + (lane&15), k = kbase + (lane>>4)*8 + e.
// A wave's per-step data = contiguous 4KB; each load instr is unit-stride 16B/lane.
__global__ __launch_bounds__(256) void wconv(const float* __restrict__ pk,
                                             const float* __restrict__ gk,
                                             u16* __restrict__ wsdot,   // 16 chunks
                                             u16* __restrict__ wsgate)  // 16 chunks
{
  int gid = blockIdx.x * 256 + threadIdx.x;   // 32768 = 128 blocks
  int t = gid >> 10, S = gid & 1023;
  int wc = S >> 8, nt = (S >> 6) & 3, lane = S & 63;
  int fr = lane & 15, kq = lane >> 4;
  int n  = wc * 64 + nt * 16 + fr;
  const float* W; int k0; u16* dst;
  if (t < 8)       { W = pk; k0 =       t      * 32; dst = wsdot  + (size_t)t * 8192; }
  else if (t < 16) { W = pk; k0 = 512 + (t-8)  * 32; dst = wsdot  + (size_t)t * 8192; }
  else if (t < 24) { W = gk; k0 =       (t-16) * 32; dst = wsgate + (size_t)(t-16) * 8192; }
  else             { W = gk; k0 = 256 + (t-24) * 32; dst = wsgate + (size_t)(t-24) * 8192; }
  int kb = k0 + kq * 8;
  u32 ow[4];
  #pragma unroll
  for (int e = 0; e < 4; ++e) {
    float f0 = W[(size_t)(kb + 2*e)     * 256 + n];
    float f1 = W[(size_t)(kb + 2*e + 1) * 256 + n];
    ow[e] = (u32)f2bf(f0) | ((u32)f2bf(f1) << 16);
  }
  *(u32x4*)(dst + (size_t)S * 8) = (u32x4){ow[0], ow[1], ow[2], ow[3]};
}

// ---------------- kernel 2: per-(b,h) partial sums of h_norm over w ----------------
__global__ __launch_bounds__(256) void ln_partial(const float* __restrict__ x,
                                                  const float* __restrict__ g,
                                                  const float* __restrict__ bt,
                                                  float* __restrict__ partial) // [768][256]
{
  const int bh = blockIdx.x;
  const int tid = threadIdx.x;
  const int wv = tid >> 6, lane = tid & 63;
  const float* xrow = x + (size_t)bh * 96 * 256;
  __shared__ float red[4][256];

  f32x4 gv = *(const f32x4*)(g  + lane * 4);
  f32x4 bv = *(const f32x4*)(bt + lane * 4);
  f32x4 acc = {0.f, 0.f, 0.f, 0.f};

  for (int w = wv; w < 96; w += 4) {
    f32x4 v = *(const f32x4*)(xrow + w * 256 + lane * 4);
    float s  = v[0] + v[1] + v[2] + v[3];
    float s2 = v[0]*v[0] + v[1]*v[1] + v[2]*v[2] + v[3]*v[3];
    #pragma unroll
    for (int m = 1; m < 64; m <<= 1) { s += __shfl_xor(s, m); s2 += __shfl_xor(s2, m); }
    float mu  = s * (1.f / 256.f);
    float var = s2 * (1.f / 256.f) - mu * mu;
    float rs  = rsqrtf(var + LN_EPS);
    #pragma unroll
    for (int j = 0; j < 4; ++j) acc[j] += (v[j] - mu) * rs * gv[j] + bv[j];
  }
  *(f32x4*)(&red[wv][lane * 4]) = acc;
  __syncthreads();
  float s = red[0][tid] + red[1][tid] + red[2][tid] + red[3][tid];
  partial[(size_t)bh * 256 + tid] = s;
}

// ---------------- kernel 3: reduce rows -> spatial mean [8][258] (wrap-padded) -----
__global__ __launch_bounds__(256) void ln_mean(const float* __restrict__ partial,
                                               float* __restrict__ mean)
{
  int b = blockIdx.x, c = threadIdx.x;
  float s = 0.f;
  for (int h = 0; h < 96; ++h) s += partial[((size_t)b * 96 + h) * 256 + c];
  float m = s * (1.f / 9216.f);
  mean[b * 258 + c] = m;
  if (c < 2) mean[b * 258 + 256 + c] = m;
}

// ---------------- kernel 4: fold wedge into per-batch weights (new layout) ---------
__global__ __launch_bounds__(256) void wfold(const float* __restrict__ pk,
                                             const float* __restrict__ meang,
                                             u16* __restrict__ wsW)
{
  __shared__ float msh[256];
  int gid = blockIdx.x * 256 + threadIdx.x;   // 65536 = 256 blocks
  int chunk = gid >> 10;                      // 0..63 (uniform per block)
  int b = chunk >> 3, j = chunk & 7;
  msh[threadIdx.x] = meang[b * 258 + threadIdx.x];
  __syncthreads();
  int S = gid & 1023;
  int wc = S >> 8, nt = (S >> 6) & 3, lane = S & 63;
  int fr = lane & 15, kq = lane >> 4;
  int n  = wc * 64 + nt * 16 + fr;
  u32 ow[4];
  #pragma unroll
  for (int e = 0; e < 4; ++e) {
    float r[2];
    #pragma unroll
    for (int hh = 0; hh < 2; ++hh) {
      int c = j * 32 + kq * 8 + 2 * e + hh;
      int cm1 = (c + 255) & 255, cm2 = (c + 254) & 255;
      int cp1 = (c + 1) & 255,   cp2 = (c + 2) & 255;
      r[hh] = msh[cm1] * pk[(size_t)(256 + cm1) * 256 + n]
            - msh[cp1] * pk[(size_t)(256 + c)   * 256 + n]
            + msh[cm2] * pk[(size_t)(768 + cm2) * 256 + n]
            - msh[cp2] * pk[(size_t)(768 + c)   * 256 + n];
    }
    ow[e] = (u32)f2bf(r[0]) | ((u32)f2bf(r[1]) << 16);
  }
  *(u32x4*)(wsW + (size_t)chunk * 8192 + (size_t)S * 8) = (u32x4){ow[0], ow[1], ow[2], ow[3]};
}

// ---------------- kernel 5: fused main ---------------------------------------------
// r11 structure EXACTLY; only __launch_bounds__ 2nd arg 4 -> 2. Empirically the 2nd
// arg behaves CUDA-style (min BLOCKS/CU): (512,4) capped VGPR at 64 and r11's ~115-reg
// demand spilled 300+MB to scratch. (512,2) -> 16 waves/CU cap -> 128 VGPRs available.
__global__ __launch_bounds__(512, 2) void fused(
    const float* __restrict__ x,
    const float* __restrict__ lng, const float* __restrict__ lnb,
    const u16* __restrict__ wsdot, const u16* __restrict__ wsW,
    const u16* __restrict__ wsgate,
    const float* __restrict__ pbias, const float* __restrict__ gbias,
    const float* __restrict__ gamma, const float* __restrict__ meang,
    float* __restrict__ out)
{
  __shared__ u16 hn[MROW * HSTR];       // 33792 B  h_norm bf16 (persists, read-only after preproc)
  __shared__ u16 afg[2][MROW * ASTR];   // 10240 B  g_feat chunk dbuf (seg 4 only)
  __shared__ float mshp[2][256];        //  2048 B  mshp[s-1][c] = mean[c+s]

  const int tid  = threadIdx.x;
  const long pix0 = (long)blockIdx.x * MROW;
  const int bat  = (int)(pix0 / HWPIX);      // 9216 % 64 == 0

  const int wave = tid >> 6, lane = tid & 63;
  const int wr = wave & 1, wc = wave >> 1;       // 2x4 wave grid
  const int fr = lane & 15, kq = lane >> 4;

  if (tid < 256) {
    mshp[0][tid] = meang[bat * 258 + tid + 1];
    mshp[1][tid] = meang[bat * 258 + tid + 2];
  }

  f32x4 acc[2][4];
  #pragma unroll
  for (int i = 0; i < 2; ++i)
    #pragma unroll
    for (int j = 0; j < 4; ++j) acc[i][j] = (f32x4){0.f, 0.f, 0.f, 0.f};
  u32 gfp[2][4][2];

  // ---- B register ring: two named sets, parity = chunk & 1 ----
  u32x4 b0[4], b1[4];
  auto sgbase = [&](auto SEGC) -> const u16* {
    constexpr int sg = decltype(SEGC)::value;
    if constexpr      (sg == 0) return wsdot;
    else if constexpr (sg == 1) return wsdot + 8 * 8192;
    else if constexpr (sg == 2) return wsW + (size_t)bat * 65536;
    else if constexpr (sg == 3) return wsgate;
    else                        return wsgate + 8 * 8192;
  };
  auto loadB = [&](auto CH) {
    constexpr int ch = decltype(CH)::value;
    const u16* s0 = sgbase(IC<(ch >> 3)>{}) + (size_t)(ch & 7) * 8192 + wc * 2048 + lane * 8;
    if constexpr ((ch & 1) == 0) {
      b0[0] = *(const u32x4*)(s0);        b0[1] = *(const u32x4*)(s0 + 512);
      b0[2] = *(const u32x4*)(s0 + 1024); b0[3] = *(const u32x4*)(s0 + 1536);
    } else {
      b1[0] = *(const u32x4*)(s0);        b1[1] = *(const u32x4*)(s0 + 512);
      b1[2] = *(const u32x4*)(s0 + 1024); b1[3] = *(const u32x4*)(s0 + 1536);
    }
  };

  loadB(IC<0>{});                     // chunk 0 -> set 0; lands during preproc

  float pbv[4];
  #pragma unroll
  for (int nt = 0; nt < 4; ++nt) pbv[nt] = pbias[wc * 64 + nt * 16 + fr];

  // ---- preproc (2-pass): LN -> hn (8 lanes/pixel, 32 ch each) ----
  {
    const int p = tid >> 3, o = tid & 7;
    const float* xp = x + (pix0 + p) * 256 + o * 32;
    float s = 0.f, s2 = 0.f;
    #pragma unroll
    for (int i = 0; i < 8; ++i) {
      f32x4 v = *(const f32x4*)(xp + i * 4);
      s  += v[0] + v[1] + v[2] + v[3];
      s2 += v[0]*v[0] + v[1]*v[1] + v[2]*v[2] + v[3]*v[3];
    }
    s += __shfl_xor(s, 1); s2 += __shfl_xor(s2, 1);
    s += __shfl_xor(s, 2); s2 += __shfl_xor(s2, 2);
    s += __shfl_xor(s, 4); s2 += __shfl_xor(s2, 4);
    float mu  = s * (1.f / 256.f);
    float var = s2 * (1.f / 256.f) - mu * mu;
    float rs  = rsqrtf(var + LN_EPS);

    const float* gp = lng + o * 32;
    const float* bp = lnb + o * 32;
    u16* zd = hn + p * HSTR + o * 32;
    #pragma unroll
    for (int i = 0; i < 8; ++i) {
      f32x4 v  = *(const f32x4*)(xp + i * 4);     // L2-hot reload
      f32x4 gg = *(const f32x4*)(gp + i * 4);
      f32x4 bb = *(const f32x4*)(bp + i * 4);
      float h0 = (v[0] - mu) * rs * gg[0] + bb[0];
      float h1 = (v[1] - mu) * rs * gg[1] + bb[1];
      float h2 = (v[2] - mu) * rs * gg[2] + bb[2];
      float h3 = (v[3] - mu) * rs * gg[3] + bb[3];
      u32 d0 = pkbf(h0, h1);
      u32 d1 = pkbf(h2, h3);
      *(u32*)(zd + i * 4)     = d0;
      *(u32*)(zd + i * 4 + 2) = d1;
      if (i == 0 && o == 0) *(u32*)(hn + p * HSTR + 256) = d0;  // wrap pad ch[256,257]
    }
  }

  // lane-local feats: A fragment for shift s, window w, one hn row -> bf16x8
  auto featsRow = [&](auto SC, int w, int row) -> bf16x8 {
    constexpr int s = decltype(SC)::value;
    const int cc = w * 32 + kq * 8;
    const u16* zp = hn + row * HSTR + cc;
    u32x4 hv = *(const u32x4*)(zp);            // h0..h7
    u32  hx  = *(const u32*)(zp + 8);          // h8,h9
    float h0 = lo2f(hv[0]), h1 = hi2f(hv[0]), h2 = lo2f(hv[1]), h3 = hi2f(hv[1]);
    float h4 = lo2f(hv[2]), h5 = hi2f(hv[2]), h6 = lo2f(hv[3]), h7 = hi2f(hv[3]);
    float h8 = lo2f(hx),  h9 = hi2f(hx);
    const float* mp = &mshp[s - 1][cc];        // broadcast within 16-lane group
    f32x4 ma = *(const f32x4*)(mp);
    f32x4 mb = *(const f32x4*)(mp + 4);
    float t0, t1, t2, t3, t4, t5, t6, t7;
    if constexpr (s == 1) { t0=h1; t1=h2; t2=h3; t3=h4; t4=h5; t5=h6; t6=h7; t7=h8; }
    else                  { t0=h2; t1=h3; t2=h4; t3=h5; t4=h6; t5=h7; t6=h8; t7=h9; }
    float r0 = fsilu(h0 * (t0 - ma[0]));
    float r1 = fsilu(h1 * (t1 - ma[1]));
    float r2 = fsilu(h2 * (t2 - ma[2]));
    float r3 = fsilu(h3 * (t3 - ma[3]));
    float r4 = fsilu(h4 * (t4 - mb[0]));
    float r5 = fsilu(h5 * (t5 - mb[1]));
    float r6 = fsilu(h6 * (t6 - mb[2]));
    float r7 = fsilu(h7 * (t7 - mb[3]));
    u32x4 o_;
    o_[0] = pkbf(r0, r1); o_[1] = pkbf(r2, r3);
    o_[2] = pkbf(r4, r5); o_[3] = pkbf(r6, r7);
    return __builtin_bit_cast(bf16x8, o_);
  };

  // g_feat chunk cg (compile-time) from packed regs into afg (seg 4 only)
  auto gfcopy = [&](auto CGC, int buf) {
    constexpr int cg = decltype(CGC)::value;
    constexpr int par = cg & 1;
    if (wc == (cg >> 1)) {
      #pragma unroll
      for (int v = 0; v < 2; ++v) {
        #pragma unroll
        for (int ai = 0; ai < 2; ++ai)
          #pragma unroll
          for (int rp = 0; rp < 2; ++rp) {
            u32 pw = gfp[ai][par * 2 + v][rp];
            int row0 = wr * 32 + ai * 16 + kq * 4 + rp * 2;
            afg[buf][row0 * ASTR + v * 16 + fr]       = (u16)pw;
            afg[buf][(row0 + 1) * ASTR + v * 16 + fr] = (u16)(pw >> 16);
          }
      }
    }
  };

  auto domfma = [&](bf16x8 av0, bf16x8 av1, auto PAR) {
    __builtin_amdgcn_s_setprio(1);
    #pragma unroll
    for (int nt = 0; nt < 4; ++nt) {
      bf16x8 bv;
      if constexpr (decltype(PAR)::value == 0) bv = __builtin_bit_cast(bf16x8, b0[nt]);
      else                                     bv = __builtin_bit_cast(bf16x8, b1[nt]);
      acc[0][nt] = __builtin_amdgcn_mfma_f32_16x16x32_bf16(av0, bv, acc[0][nt], 0, 0, 0);
      acc[1][nt] = __builtin_amdgcn_mfma_f32_16x16x32_bf16(av1, bv, acc[1][nt], 0, 0, 0);
    }
    __builtin_amdgcn_s_setprio(0);
  };

  __syncthreads();                    // hn, mshp visible — the ONLY barrier until seg 4

  auto stepfn = [&](auto TC) {
    constexpr int t   = decltype(TC)::value;
    constexpr int seg = t >> 3, loc = t & 7;
    constexpr int u   = t + 1;
    if constexpr (u < 40) loadB(IC<u>{});     // into set (u&1); used next step
    bf16x8 av0, av1;
    if constexpr (seg == 0) {
      av0 = featsRow(IC<1>{}, loc, wr * 32 + fr);
      av1 = featsRow(IC<1>{}, loc, wr * 32 + 16 + fr);
    } else if constexpr (seg == 1) {
      av0 = featsRow(IC<2>{}, loc, wr * 32 + fr);
      av1 = featsRow(IC<2>{}, loc, wr * 32 + 16 + fr);
    } else if constexpr (seg == 2 || seg == 3) {
      const u16* ar = hn + (wr * 32 + fr) * HSTR + loc * 32 + kq * 8;
      av0 = *(const bf16x8*)(ar);
      av1 = *(const bf16x8*)(ar + 16 * HSTR);
    } else {
      const u16* ar = &afg[t & 1][(wr * 32 + fr) * ASTR + kq * 8];
      av0 = *(const bf16x8*)(ar);
      av1 = *(const bf16x8*)(ar + 16 * ASTR);
    }
    domfma(av0, av1, IC<t & 1>{});
    if constexpr (t == 23) {          // end of GEMM1: fold to packed bf16 g_feat
      #pragma unroll
      for (int nt = 0; nt < 4; ++nt)
        #pragma unroll
        for (int ai = 0; ai < 2; ++ai) {
          f32x4 a = acc[ai][nt];
          gfp[ai][nt][0] = pkbf(a[0] + pbv[nt], a[1] + pbv[nt]);
          gfp[ai][nt][1] = pkbf(a[2] + pbv[nt], a[3] + pbv[nt]);
          acc[ai][nt] = (f32x4){0.f, 0.f, 0.f, 0.f};
        }
    }
    if constexpr (t >= 31 && t < 39) {        // produce g_feat A-chunk for step t+1
      gfcopy(IC<t - 31>{}, (t + 1) & 1);
      __syncthreads();
    }
  };
  auto run8 = [&](auto B8) {
    constexpr int b8 = decltype(B8)::value;
    stepfn(IC<b8 + 0>{}); stepfn(IC<b8 + 1>{}); stepfn(IC<b8 + 2>{}); stepfn(IC<b8 + 3>{});
    stepfn(IC<b8 + 4>{}); stepfn(IC<b8 + 5>{}); stepfn(IC<b8 + 6>{}); stepfn(IC<b8 + 7>{});
  };
  run8(IC<0>{}); run8(IC<8>{}); run8(IC<16>{}); run8(IC<24>{}); run8(IC<32>{});

  // ---- final epilogue: alpha, silu, LayerScale, residual ----
  float gbv[4], gmv[4];
  #pragma unroll
  for (int nt = 0; nt < 4; ++nt) {
    int col = wc * 64 + nt * 16 + fr;
    gbv[nt] = gbias[col]; gmv[nt] = gamma[col];
  }
  #pragma unroll
  for (int ai = 0; ai < 2; ++ai)
    #pragma unroll
    for (int rr = 0; rr < 4; ++rr) {
      const int row = wr * 32 + ai * 16 + kq * 4 + rr;
      const long pix = pix0 + row;
      #pragma unroll
      for (int nt = 0; nt < 4; ++nt) {
        int col = wc * 64 + nt * 16 + fr;
        float xv = x[pix * 256 + col];
        float hh = bfu2f(hn[row * HSTR + col]);
        u32 pw = gfp[ai][nt][rr >> 1];
        float gfv = bfu2f((u16)((rr & 1) ? (pw >> 16) : pw));
        float al = fsigmoid(acc[ai][nt][rr] + gbv[nt]);
        out[pix * 256 + col] = xv + (fsilu(hh) + al * gfv) * gmv[nt];
      }
    }
}

extern "C" void kernel_launch(void* const* d_in, const int* in_sizes, int n_in,
                              void* d_out, int out_size, void* d_ws, size_t ws_size,
                              hipStream_t stream) {
  const float* x     = (const float*)d_in[0];
  const float* lng   = (const float*)d_in[1];
  const float* lnb   = (const float*)d_in[2];
  const float* pk    = (const float*)d_in[3];
  const float* pbias = (const float*)d_in[4];
  const float* gk    = (const float*)d_in[5];
  const float* gbias = (const float*)d_in[6];
  const float* gamma = (const float*)d_in[7];
  float* out = (float*)d_out;

  char* ws = (char*)d_ws;
  u16*   wsdot   = (u16*)ws;                       // 262144 B (16 chunks)
  u16*   wsgate  = (u16*)(ws + 262144);            // 262144 B (16 chunks)
  float* meang   = (float*)(ws + 524288);          // 8256 B
  u16*   wsW     = (u16*)(ws + 532544);            // 1048576 B (64 chunks, per-batch W')
  float* partial = (float*)(ws + 532544);          // 786432 B — dead before wfold writes W'

  wconv<<<128, 256, 0, stream>>>(pk, gk, wsdot, wsgate);
  ln_partial<<<768, 256, 0, stream>>>(x, lng, lnb, partial);
  ln_mean<<<8, 256, 0, stream>>>(partial, meang);
  wfold<<<256, 256, 0, stream>>>(pk, meang, wsW);
  fused<<<NPIX / MROW, 512, 0, stream>>>(x, lng, lnb, wsdot, wsW, wsgate,
                                         pbias, gbias, gamma, meang, out);
}

// Round 13
// 151.254 us; speedup vs baseline: 1.7892x; 1.4864x over previous
//
#include <hip/hip_runtime.h>
#include <hip/hip_bf16.h>

typedef unsigned short u16;
typedef unsigned int   u32;
typedef __attribute__((ext_vector_type(2))) float f32x2;
typedef __attribute__((ext_vector_type(4))) float f32x4;
typedef __attribute__((ext_vector_type(4))) u32   u32x4;
typedef __attribute__((ext_vector_type(8))) short bf16x8;

#define HWPIX  9216
#define NPIX   73728
#define LN_EPS 1e-5f
#define MROW   64       // pixels per block
#define ASTR   40       // afg chunk row stride (elems): 32 + 8 pad

template<int N> struct IC { static constexpr int value = N; };

__device__ __forceinline__ u16 f2bf(float f){
  u32 u = __builtin_bit_cast(u32, f);
  u += 0x7fffu + ((u >> 16) & 1u);          // RTNE
  return (u16)(u >> 16);
}
__device__ __forceinline__ u32 pkbf(float lo, float hi){   // 1 inst packed cvt
  u32 d;
  asm("v_cvt_pk_bf16_f32 %0, %1, %2" : "=v"(d) : "v"(lo), "v"(hi));
  return d;
}
__device__ __forceinline__ float bfu2f(u16 h){ return __builtin_bit_cast(float, (u32)h << 16); }
__device__ __forceinline__ float fsigmoid(float v){ return __fdividef(1.f, 1.f + __expf(-v)); }
__device__ __forceinline__ float fsilu(float v){ return __fdividef(v, 1.f + __expf(-v)); }

__device__ __forceinline__ void gld16(const u16* g, u16* l){
  __builtin_amdgcn_global_load_lds((const __attribute__((address_space(1))) void*)g,
                                   (__attribute__((address_space(3))) void*)l,
                                   16, 0, 0);
}

// ---------------- kernel 1: weight convert (dot + gate) into staging layout --------
// (r10-validated) chunk t, slot S: n = (S>>9)*128 + ((S>>6)&7)*16 + ((S>>2)&15),
// pp = S&3, content k-quarter kq = pp ^ ((((S>>2)&15)>>1)&3)  (XOR bank swizzle).
__global__ __launch_bounds__(256) void wconv(const float* __restrict__ pk,
                                             const float* __restrict__ gk,
                                             u16* __restrict__ wsdot,   // 16 chunks
                                             u16* __restrict__ wsgate)  // 16 chunks
{
  int gid = blockIdx.x * 256 + threadIdx.x;   // 32768 = 128 blocks
  int t = gid >> 10, S = gid & 1023;
  int q = (S >> 2) & 15, pp = S & 3, w8 = (S >> 6) & 7, rb = S >> 9;
  int n  = rb * 128 + w8 * 16 + q;
  int kq = pp ^ ((q >> 1) & 3);
  const float* W; int k0; u16* dst;
  if (t < 8)       { W = pk; k0 =       t      * 32 + kq * 8; dst = wsdot  + (size_t)t * 8192; }
  else if (t < 16) { W = pk; k0 = 512 + (t-8)  * 32 + kq * 8; dst = wsdot  + (size_t)t * 8192; }
  else             { W = gk; k0 =       (t-16) * 32 + kq * 8; dst = wsgate + (size_t)(t-16) * 8192; }
  u32 ow[4];
  #pragma unroll
  for (int e = 0; e < 4; ++e) {
    float f0 = W[(size_t)(k0 + 2*e)     * 256 + n];
    float f1 = W[(size_t)(k0 + 2*e + 1) * 256 + n];
    ow[e] = (u32)f2bf(f0) | ((u32)f2bf(f1) << 16);
  }
  *(u32x4*)(dst + (size_t)S * 8) = (u32x4){ow[0], ow[1], ow[2], ow[3]};
}

// ---------------- kernel 2: per-pixel LN stats + per-(b,h) partial sums ------------
// (r4-validated) mu_rs[73728][2] + partial[768][256]
__global__ __launch_bounds__(256) void prep(const float* __restrict__ x,
                                            const float* __restrict__ g,
                                            const float* __restrict__ bt,
                                            float* __restrict__ mu_rs,
                                            float* __restrict__ partial)
{
  const int bh = blockIdx.x;
  const int tid = threadIdx.x;
  const int wv = tid >> 6, lane = tid & 63;
  const float* xrow = x + (size_t)bh * 96 * 256;
  __shared__ float red[4][256];

  f32x4 gv = *(const f32x4*)(g  + lane * 4);
  f32x4 bv = *(const f32x4*)(bt + lane * 4);
  f32x4 acc = {0.f, 0.f, 0.f, 0.f};

  for (int w = wv; w < 96; w += 4) {
    f32x4 v = *(const f32x4*)(xrow + w * 256 + lane * 4);
    float s  = v[0] + v[1] + v[2] + v[3];
    float s2 = v[0]*v[0] + v[1]*v[1] + v[2]*v[2] + v[3]*v[3];
    #pragma unroll
    for (int m = 1; m < 64; m <<= 1) { s += __shfl_xor(s, m); s2 += __shfl_xor(s2, m); }
    float mu  = s * (1.f / 256.f);
    float var = s2 * (1.f / 256.f) - mu * mu;
    float rs  = rsqrtf(var + LN_EPS);
    if (lane == 0) *(f32x2*)(mu_rs + (size_t)(bh * 96 + w) * 2) = f32x2{mu, rs};
    #pragma unroll
    for (int j = 0; j < 4; ++j) acc[j] += (v[j] - mu) * rs * gv[j] + bv[j];
  }
  *(f32x4*)(&red[wv][lane * 4]) = acc;
  __syncthreads();
  float s = red[0][tid] + red[1][tid] + red[2][tid] + red[3][tid];
  partial[(size_t)bh * 256 + tid] = s;
}

// ---------------- kernel 3: reduce rows -> spatial mean [8][258] (wrap-padded) -----
__global__ __launch_bounds__(256) void ln_mean(const float* __restrict__ partial,
                                               float* __restrict__ mean)
{
  int b = blockIdx.x, c = threadIdx.x;
  float s = 0.f;
  for (int h = 0; h < 96; ++h) s += partial[((size_t)b * 96 + h) * 256 + c];
  float m = s * (1.f / 9216.f);
  mean[b * 258 + c] = m;
  if (c < 2) mean[b * 258 + 256 + c] = m;
}

// ---------------- kernel 4: fold wedge into per-batch weights (r10-validated) ------
__global__ __launch_bounds__(256) void wfold(const float* __restrict__ pk,
                                             const float* __restrict__ meang,
                                             u16* __restrict__ wsW)
{
  __shared__ float msh[256];
  int gid = blockIdx.x * 256 + threadIdx.x;   // 65536 = 256 blocks
  int chunk = gid >> 10;
  int b = chunk >> 3, j = chunk & 7;
  msh[threadIdx.x] = meang[b * 258 + threadIdx.x];
  __syncthreads();
  int S = gid & 1023;
  int q = (S >> 2) & 15, pp = S & 3, w8 = (S >> 6) & 7, rb = S >> 9;
  int n  = rb * 128 + w8 * 16 + q;
  int kq = pp ^ ((q >> 1) & 3);
  u32 ow[4];
  #pragma unroll
  for (int e = 0; e < 4; ++e) {
    float r[2];
    #pragma unroll
    for (int hh = 0; hh < 2; ++hh) {
      int c = j * 32 + kq * 8 + 2 * e + hh;
      int cm1 = (c + 255) & 255, cm2 = (c + 254) & 255;
      int cp1 = (c + 1) & 255,   cp2 = (c + 2) & 255;
      r[hh] = msh[cm1] * pk[(size_t)(256 + cm1) * 256 + n]
            - msh[cp1] * pk[(size_t)(256 + c)   * 256 + n]
            + msh[cm2] * pk[(size_t)(768 + cm2) * 256 + n]
            - msh[cp2] * pk[(size_t)(768 + c)   * 256 + n];
    }
    ow[e] = (u32)f2bf(r[0]) | ((u32)f2bf(r[1]) << 16);
  }
  *(u32x4*)(wsW + (size_t)chunk * 8192 + (size_t)S * 8) = (u32x4){ow[0], ow[1], ow[2], ow[3]};
}

// ---------------- kernel 5: fused main ---------------------------------------------
// r10 skeleton, hn ELIMINATED: all A-chunks built from x + mu_rs (lane-local LN).
// Freed LDS buys a depth-3 B DMA ring -> counted s_waitcnt vmcnt(2) per step (never
// draining the newest stage). LDS 63KB -> 2 blocks/CU. One barrier per step, 40 steps.
__global__ __launch_bounds__(512, 2) void fused(
    const float* __restrict__ x,
    const float* __restrict__ lng, const float* __restrict__ lnb,
    const u16* __restrict__ wsdot, const u16* __restrict__ wsW,
    const u16* __restrict__ wsgate, const float* __restrict__ mu_rs,
    const float* __restrict__ pbias, const float* __restrict__ gbias,
    const float* __restrict__ gamma, const float* __restrict__ meang,
    float* __restrict__ out)
{
  __shared__ u16 afg[2][MROW * ASTR];   // 10240 B  A chunk dbuf (all segs)
  __shared__ u16 Bl [3][8192];          // 49152 B  B DMA ring (depth 3)
  __shared__ float gshb[2][260];        //  2080 B  ln gamma/beta (wrap-padded 4)
  __shared__ float msh[258];            //  1032 B  spatial mean (wrap-padded)
  __shared__ float mursh[128];          //   512 B  per-row {mu, rs}

  const int tid  = threadIdx.x;
  const long pix0 = (long)blockIdx.x * MROW;
  const int bat  = (int)(pix0 / HWPIX);      // 9216 % 64 == 0

  const int wave = tid >> 6, lane = tid & 63;
  const int wr = wave & 1, wc = wave >> 1;       // 2x4 wave grid
  const int fr = lane & 15, kq = lane >> 4;
  const int bswz = (kq ^ ((fr >> 1) & 3)) * 8;
  const int brow = tid >> 3, o4 = (tid & 7) * 4; // A-build: row, 4-ch slice

  auto sgbase = [&](auto SEGC) -> const u16* {
    constexpr int sg = decltype(SEGC)::value;
    if constexpr      (sg == 0) return wsdot;
    else if constexpr (sg == 1) return wsdot + 8 * 8192;
    else if constexpr (sg == 2) return wsW + (size_t)bat * 65536;
    else if constexpr (sg == 3) return wsgate;
    else                        return wsgate + 8 * 8192;
  };
  auto stage = [&](auto UC, auto SL) {    // DMA chunk u -> ring slot sl
    constexpr int u  = decltype(UC)::value;
    constexpr int sl = decltype(SL)::value;
    const u16* src = sgbase(IC<(u >> 3)>{}) + (size_t)(u & 7) * 8192 + tid * 8;
    u16* dst = &Bl[sl][wave * 512];       // wave-uniform base; HW adds lane*16B
    gld16(src, dst);
    gld16(src + 4096, dst + 4096);
  };

  stage(IC<0>{}, IC<0>{});
  stage(IC<1>{}, IC<1>{});

  // ---- table fill ----
  if (tid < 256)      { gshb[0][tid] = lng[tid]; gshb[1][tid] = lnb[tid]; }
  else if (tid < 260) { int c = tid - 256; gshb[0][256 + c] = lng[c]; gshb[1][256 + c] = lnb[c]; }
  if (tid < 258) msh[tid] = meang[bat * 258 + tid];
  if (tid < 128) mursh[tid] = mu_rs[pix0 * 2 + tid];

  f32x4 acc[2][4];
  #pragma unroll
  for (int i = 0; i < 2; ++i)
    #pragma unroll
    for (int j = 0; j < 4; ++j) acc[i][j] = (f32x4){0.f, 0.f, 0.f, 0.f};
  u32 gfp[2][4][2];
  float pbv[4];
  #pragma unroll
  for (int nt = 0; nt < 4; ++nt) pbv[nt] = pbias[wc * 64 + nt * 16 + fr];

  __syncthreads();                    // tables + stage(0,1) all drained (prologue only)

  const float* xrowp = x + (pix0 + brow) * 256;
  const float muv = mursh[brow * 2];
  const float rsv = mursh[brow * 2 + 1];

  // dot feats chunk (shift s, window w) -> afg[buf]; h computed from x on the fly
  auto featsB = [&](auto SC, int w, int buf) {
    constexpr int s = decltype(SC)::value;
    const int cc = w * 32 + o4;
    f32x4 xa = *(const f32x4*)(xrowp + cc);
    f32x4 xb = (cc == 252) ? *(const f32x4*)(xrowp) : *(const f32x4*)(xrowp + cc + 4);
    float h[8];
    #pragma unroll
    for (int j = 0; j < 4; ++j) h[j]     = (xa[j] - muv) * rsv * gshb[0][cc + j]     + gshb[1][cc + j];
    #pragma unroll
    for (int j = 0; j < 4; ++j) h[4 + j] = (xb[j] - muv) * rsv * gshb[0][cc + 4 + j] + gshb[1][cc + 4 + j];
    float r0 = fsilu(h[0] * (h[0 + s] - msh[cc + s]));
    float r1 = fsilu(h[1] * (h[1 + s] - msh[cc + 1 + s]));
    float r2 = fsilu(h[2] * (h[2 + s] - msh[cc + 2 + s]));
    float r3 = fsilu(h[3] * (h[3 + s] - msh[cc + 3 + s]));
    *(u32*)(&afg[buf][brow * ASTR + o4])     = pkbf(r0, r1);
    *(u32*)(&afg[buf][brow * ASTR + o4 + 2]) = pkbf(r2, r3);
  };
  // plain h_norm chunk (window w) -> afg[buf]
  auto hB = [&](int w, int buf) {
    const int cc = w * 32 + o4;
    f32x4 xa = *(const f32x4*)(xrowp + cc);
    float h0 = (xa[0] - muv) * rsv * gshb[0][cc]     + gshb[1][cc];
    float h1 = (xa[1] - muv) * rsv * gshb[0][cc + 1] + gshb[1][cc + 1];
    float h2 = (xa[2] - muv) * rsv * gshb[0][cc + 2] + gshb[1][cc + 2];
    float h3 = (xa[3] - muv) * rsv * gshb[0][cc + 3] + gshb[1][cc + 3];
    *(u32*)(&afg[buf][brow * ASTR + o4])     = pkbf(h0, h1);
    *(u32*)(&afg[buf][brow * ASTR + o4 + 2]) = pkbf(h2, h3);
  };
  // g_feat chunk cg from packed regs into afg
  auto gfcopy = [&](auto CGC, int buf) {
    constexpr int cg = decltype(CGC)::value;
    constexpr int par = cg & 1;
    if (wc == (cg >> 1)) {
      #pragma unroll
      for (int v = 0; v < 2; ++v) {
        #pragma unroll
        for (int ai = 0; ai < 2; ++ai)
          #pragma unroll
          for (int rp = 0; rp < 2; ++rp) {
            u32 pw = gfp[ai][par * 2 + v][rp];
            int row0 = wr * 32 + ai * 16 + kq * 4 + rp * 2;
            afg[buf][row0 * ASTR + v * 16 + fr]       = (u16)pw;
            afg[buf][(row0 + 1) * ASTR + v * 16 + fr] = (u16)(pw >> 16);
          }
      }
    }
  };

  auto domfma = [&](auto AB, auto SL) {
    constexpr int ab = decltype(AB)::value, sl = decltype(SL)::value;
    const u16* ar = &afg[ab][(wr * 32 + fr) * ASTR + kq * 8];
    bf16x8 av0 = *(const bf16x8*)(ar);
    bf16x8 av1 = *(const bf16x8*)(ar + 16 * ASTR);
    const u16* bp = &Bl[sl][wc * 2048 + fr * 32 + bswz];
    __builtin_amdgcn_s_setprio(1);
    #pragma unroll
    for (int nt = 0; nt < 4; ++nt) {
      bf16x8 bv = *(const bf16x8*)(bp + nt * 512);
      acc[0][nt] = __builtin_amdgcn_mfma_f32_16x16x32_bf16(av0, bv, acc[0][nt], 0, 0, 0);
      acc[1][nt] = __builtin_amdgcn_mfma_f32_16x16x32_bf16(av1, bv, acc[1][nt], 0, 0, 0);
    }
    __builtin_amdgcn_s_setprio(0);
  };

  featsB(IC<1>{}, 0, 0);              // afg[0] = dot s=1 window 0
  asm volatile("s_waitcnt lgkmcnt(0)" ::: "memory");
  __builtin_amdgcn_s_barrier();       // afg[0] visible

  auto stepfn = [&](auto TC) {
    constexpr int t = decltype(TC)::value;
    constexpr int u = t + 1;          // chunk to build
    // ---- build next A-chunk (x loads consumed in-step, before stage issue) ----
    if constexpr (u < 8)       featsB(IC<1>{}, u & 7, u & 1);
    else if constexpr (u < 16) featsB(IC<2>{}, u & 7, u & 1);
    else if constexpr (u < 32) hB(u & 7, u & 1);
    else if constexpr (u < 40) gfcopy(IC<u - 32>{}, u & 1);
    // ---- MFMA on current chunk ----
    domfma(IC<t & 1>{}, IC<t % 3>{});
    if constexpr (t == 23) {          // end of GEMM1: fold to packed bf16 g_feat
      #pragma unroll
      for (int nt = 0; nt < 4; ++nt)
        #pragma unroll
        for (int ai = 0; ai < 2; ++ai) {
          f32x4 a = acc[ai][nt];
          gfp[ai][nt][0] = pkbf(a[0] + pbv[nt], a[1] + pbv[nt]);
          gfp[ai][nt][1] = pkbf(a[2] + pbv[nt], a[3] + pbv[nt]);
          acc[ai][nt] = (f32x4){0.f, 0.f, 0.f, 0.f};
        }
    }
    // ---- issue stage 2 ahead (consumed at t+2; forced complete at end of t+1) ----
    if constexpr (t + 2 < 40) stage(IC<t + 2>{}, IC<(t + 2) % 3>{});
    // ---- counted drain: force stage(t+1) done, keep stage(t+2) flying ----
    if constexpr (t < 37) asm volatile("s_waitcnt vmcnt(2) lgkmcnt(0)" ::: "memory");
    else                  asm volatile("s_waitcnt vmcnt(0) lgkmcnt(0)" ::: "memory");
    __builtin_amdgcn_s_barrier();
  };
  auto run8 = [&](auto B8) {
    constexpr int b8 = decltype(B8)::value;
    stepfn(IC<b8 + 0>{}); stepfn(IC<b8 + 1>{}); stepfn(IC<b8 + 2>{}); stepfn(IC<b8 + 3>{});
    stepfn(IC<b8 + 4>{}); stepfn(IC<b8 + 5>{}); stepfn(IC<b8 + 6>{}); stepfn(IC<b8 + 7>{});
  };
  run8(IC<0>{}); run8(IC<8>{}); run8(IC<16>{}); run8(IC<24>{}); run8(IC<32>{});

  // ---- final epilogue: alpha, silu, LayerScale, residual (h recomputed from x) ----
  float gbv[4], gmv[4];
  #pragma unroll
  for (int nt = 0; nt < 4; ++nt) {
    int col = wc * 64 + nt * 16 + fr;
    gbv[nt] = gbias[col]; gmv[nt] = gamma[col];
  }
  #pragma unroll
  for (int ai = 0; ai < 2; ++ai)
    #pragma unroll
    for (int rr = 0; rr < 4; ++rr) {
      const int row = wr * 32 + ai * 16 + kq * 4 + rr;
      const long pix = pix0 + row;
      const float mu2 = mursh[row * 2], rs2 = mursh[row * 2 + 1];
      #pragma unroll
      for (int nt = 0; nt < 4; ++nt) {
        int col = wc * 64 + nt * 16 + fr;
        float xv = x[pix * 256 + col];
        float hh = (xv - mu2) * rs2 * gshb[0][col] + gshb[1][col];
        u32 pw = gfp[ai][nt][rr >> 1];
        float gfv = bfu2f((u16)((rr & 1) ? (pw >> 16) : pw));
        float al = fsigmoid(acc[ai][nt][rr] + gbv[nt]);
        out[pix * 256 + col] = xv + (fsilu(hh) + al * gfv) * gmv[nt];
      }
    }
}

extern "C" void kernel_launch(void* const* d_in, const int* in_sizes, int n_in,
                              void* d_out, int out_size, void* d_ws, size_t ws_size,
                              hipStream_t stream) {
  const float* x     = (const float*)d_in[0];
  const float* lng   = (const float*)d_in[1];
  const float* lnb   = (const float*)d_in[2];
  const float* pk    = (const float*)d_in[3];
  const float* pbias = (const float*)d_in[4];
  const float* gk    = (const float*)d_in[5];
  const float* gbias = (const float*)d_in[6];
  const float* gamma = (const float*)d_in[7];
  float* out = (float*)d_out;

  char* ws = (char*)d_ws;
  u16*   wsdot   = (u16*)ws;                       // 262144 B (16 chunks)
  u16*   wsgate  = (u16*)(ws + 262144);            // 262144 B (16 chunks)
  float* meang   = (float*)(ws + 524288);          // 8256 B
  u16*   wsW     = (u16*)(ws + 532544);            // 1048576 B (per-batch W')
  float* partial = (float*)(ws + 532544);          // 786432 B — dead before wfold writes W'
  float* mu_rs   = (float*)(ws + 1581120);         // 589824 B (total ~2.07 MB)

  wconv<<<128, 256, 0, stream>>>(pk, gk, wsdot, wsgate);
  prep<<<768, 256, 0, stream>>>(x, lng, lnb, mu_rs, partial);
  ln_mean<<<8, 256, 0, stream>>>(partial, meang);
  wfold<<<256, 256, 0, stream>>>(pk, meang, wsW);
  fused<<<NPIX / MROW, 512, 0, stream>>>(x, lng, lnb, wsdot, wsW, wsgate, mu_rs,
                                         pbias, gbias, gamma, meang, out);
}